// Round 10
// baseline (69.903 us; speedup 1.0000x reference)
//
#include <hip/hip_runtime.h>
#include <hip/hip_bf16.h>

// MeanAggregator: out[b,:] = mean over UNIQUE neigh_idx[b,:] of embed[idx,:]
// B=2048, K=32, N=50000, D=128 (f32)
//
// One WAVE (64 threads) per batch row; zero LDS, zero barriers.
// - lane t: slot = t&31 (16B float4 chunk of a row), g = t>>5 (row parity).
// - All 64 lanes load the id for `slot` (same 128B line both halves);
//   dedupe via 31 __shfl broadcasts entirely in-register (weight 0 for
//   dups instead of compaction: expected dups/row = K^2/2N ~ 0.01, so a
//   zero-weighted load is far cheaper than any serialization).
// - Gather k=0..15: row r=2k+g; (off,w) fetched by ds_bpermute shuffle;
//   one 64-lane dwordx4 wave-load = 2 full 512B rows = 1KB/instruction.
//   16 independent unrolled loads/thread -> deep vmcnt pipeline.
// - Halves combined with one __shfl_xor(.,32); lanes 0-31 store the row
//   as 32 x dwordx4 (512B coalesced).

#define KNEIGH 32
#define DIM 128

__global__ __launch_bounds__(64) void mean_agg_kernel(
    const float* __restrict__ embed,
    const int* __restrict__ neigh_idx,
    float* __restrict__ out)
{
    const int b    = blockIdx.x;
    const int t    = threadIdx.x;
    const int slot = t & 31;
    const int g    = t >> 5;

    // id for this lane's slot (halves read the same coalesced 128B line)
    const int v = neigh_idx[b * KNEIGH + slot];

    // in-register dedupe: dup=1 if an earlier slot holds the same id
    int dup = 0;
    #pragma unroll
    for (int j = 0; j < KNEIGH - 1; ++j) {
        const int vj = __shfl(v, j);           // broadcast slot j's id
        dup |= (j < slot) & (vj == v);
    }
    const float w   = dup ? 0.0f : 1.0f;
    const int   off = v * DIM;                 // element offset, max 6.4e6

    // unique count: low 32 ballot bits (halves duplicate the pattern)
    const unsigned long long m = __ballot(!dup);
    const float inv = 1.0f / (float)__popcll(m & 0xffffffffull);

    // gather: lane half g covers rows 2k+g, chunk `slot`
    float4 acc = make_float4(0.f, 0.f, 0.f, 0.f);
    #pragma unroll
    for (int k = 0; k < KNEIGH / 2; ++k) {
        const int   r    = 2 * k + g;
        const float wr   = __shfl(w, r);       // per-lane src idx -> bpermute
        const int   offr = __shfl(off, r);
        const float4 val = *reinterpret_cast<const float4*>(
            embed + offr + (slot << 2));       // 16B aligned
        acc.x = fmaf(wr, val.x, acc.x);
        acc.y = fmaf(wr, val.y, acc.y);
        acc.z = fmaf(wr, val.z, acc.z);
        acc.w = fmaf(wr, val.w, acc.w);
    }

    // fold odd-row half into even-row half
    acc.x += __shfl_xor(acc.x, 32);
    acc.y += __shfl_xor(acc.y, 32);
    acc.z += __shfl_xor(acc.z, 32);
    acc.w += __shfl_xor(acc.w, 32);

    if (t < 32) {
        float4 r;
        r.x = acc.x * inv;
        r.y = acc.y * inv;
        r.z = acc.z * inv;
        r.w = acc.w * inv;
        *reinterpret_cast<float4*>(out + b * DIM + (slot << 2)) = r;
    }
}

extern "C" void kernel_launch(void* const* d_in, const int* in_sizes, int n_in,
                              void* d_out, int out_size, void* d_ws, size_t ws_size,
                              hipStream_t stream) {
    const float* embed     = (const float*)d_in[0];
    const int*   neigh_idx = (const int*)d_in[1];
    float*       out       = (float*)d_out;

    const int B = in_sizes[1] / KNEIGH;  // 2048

    mean_agg_kernel<<<B, 64, 0, stream>>>(embed, neigh_idx, out);
}